// Round 1
// baseline (422.250 us; speedup 1.0000x reference)
//
#include <hip/hip_runtime.h>

typedef __bf16 bf16_t;
typedef __bf16 bf16x8 __attribute__((ext_vector_type(8)));
typedef __bf16 bf16x4 __attribute__((ext_vector_type(4)));
typedef float  f32x4  __attribute__((ext_vector_type(4)));

#define MFMA16(a,b,c) __builtin_amdgcn_mfma_f32_16x16x32_bf16((a),(b),(c),0,0,0)

__device__ __forceinline__ void gl_lds16(const void* g, void* l) {
    __builtin_amdgcn_global_load_lds(
        (__attribute__((address_space(1))) void*)(g),
        (__attribute__((address_space(3))) void*)(l),
        16, 0, 0);
}

// B=2 S=4096 D=2048 HQ=32 HK=HV=8 H=32 DK=DV=64 CHUNK=64 NC=64 QKV=3072 OUT=2048
static constexpr int S_TOT   = 8192;
static constexpr int D_IN    = 2048;
static constexpr int QKV     = 3072;
static constexpr int OUT_D   = 2048;
static constexpr int NCHUNK  = 64;
static constexpr int ZSTR    = 88;

// ---------------- prep: x->bf16 convert + both weight transposes, one launch ----------------
__global__ __launch_bounds__(256)
void prep(const float* __restrict__ x, bf16_t* __restrict__ xb,
          const float* __restrict__ W_in, bf16_t* __restrict__ WinT,
          const float* __restrict__ W_out, bf16_t* __restrict__ WoutT) {
    __shared__ float tile[64][65];
    const int bid = blockIdx.x;
    const int t   = threadIdx.x;
    if (bid < 16384) {
        int i = bid * 256 + t;
        f32x4 v = ((const f32x4*)x)[i];
        bf16x4 o;
        o[0] = (bf16_t)v[0]; o[1] = (bf16_t)v[1]; o[2] = (bf16_t)v[2]; o[3] = (bf16_t)v[3];
        ((bf16x4*)xb)[i] = o;
        return;
    }
    const float* in; bf16_t* out; int R, C, bx, by;
    int tb = bid - 16384;
    if (tb < 1536) { in = W_in;  out = WinT;  R = 2048; C = 3072; bx = tb % 48; by = tb / 48; }
    else { tb -= 1536; in = W_out; out = WoutT; R = 2048; C = 2048; bx = tb % 32; by = tb / 32; }
    const int r0 = by * 64, c0 = bx * 64;
#pragma unroll
    for (int p = 0; p < 4; p++) {
        int row = p * 16 + (t >> 4);
        int col = (t & 15) * 4;
        f32x4 v = *(const f32x4*)&in[(size_t)(r0 + row) * C + c0 + col];
        tile[row][col + 0] = v[0]; tile[row][col + 1] = v[1];
        tile[row][col + 2] = v[2]; tile[row][col + 3] = v[3];
    }
    __syncthreads();
#pragma unroll
    for (int p = 0; p < 4; p++) {
        int oc  = p * 16 + (t >> 4);
        int orr = (t & 15) * 4;
        bf16x4 v;
        v[0] = (bf16_t)tile[orr + 0][oc]; v[1] = (bf16_t)tile[orr + 1][oc];
        v[2] = (bf16_t)tile[orr + 2][oc]; v[3] = (bf16_t)tile[orr + 3][oc];
        *(bf16x4*)&out[(size_t)(c0 + oc) * R + r0 + orr] = v;
    }
}

// ---------------- GEMM: counted-vmcnt 3-buffer pipeline ----------------
// C[M][N] = A[M][K] * Bt[N][K]^T.  BM=128, BN=256, BK=32, 256 threads = 4 waves,
// each wave owns a 128x64 sub-tile (acc[8][4], frag reuse 8x4 -> ~512 B LDS/MFMA).
// 3 LDS buffers (72 KB), 2-tile prefetch via global_load_lds with counted
// s_waitcnt vmcnt(6) (never 0 in steady state) + raw s_barrier — loads stay in
// flight across barriers (T3+T4), setprio(1) around MFMA cluster (T5).
// Race-freedom:
//  * tile-t data landed before iter-t ds_reads: every wave executed
//    vmcnt(6) (=> tile t's 6 loads done, tile t+1's 6 outstanding) + s_barrier
//    at end of iter t-1.
//  * stage at iter t targets buf[(t+2)%3] = buffer read at iter t-1; all waves'
//    reads of it completed (lgkmcnt before their MFMA) before the end-of-iter
//    t-1 barrier, which precedes any wave's iter-t stage issue.
// XOR swizzle (chunk ^= row&3) on the *global source* per thread keeps the
// global_load_lds dest linear; frag reads apply the same XOR -> ~0 conflicts.
template<int OUT_BF16>
__global__ __launch_bounds__(256, 2)
void gemm_pipe(const bf16_t* __restrict__ A, const bf16_t* __restrict__ Bt,
               void* __restrict__ Cout, int M, int N, int K) {
    __shared__ alignas(16) bf16_t lA[3][128 * 32];
    __shared__ alignas(16) bf16_t lB[3][256 * 32];
    const int tid = threadIdx.x;
    const int nwg = gridDim.x;
    int id = blockIdx.x;
    id = (id & 7) * (nwg >> 3) + (id >> 3);      // XCD swizzle (nwg % 8 == 0)
    const int mt = M >> 7;
    const int m0 = (id % mt) * 128;
    const int n0 = (id / mt) * 256;
    const int w = tid >> 6, lane = tid & 63;
    const int l15 = lane & 15, q = lane >> 4, q4 = q * 4;
    // staging: 256 thr x 16B = 4KB/issue; A tile 8KB = 2 issues, B tile 16KB = 4
    const int trow = tid >> 2;                    // 0..63
    const int scc  = (tid & 3) ^ (trow & 3);      // swizzled source k-chunk
    const bf16_t* Ag = A  + (size_t)(m0 + trow) * K + scc * 8;
    const bf16_t* Bg = Bt + (size_t)(n0 + trow) * K + scc * 8;
    const size_t r64 = (size_t)64 * K;
    // frag reads: row r = base16 + l15 -> r&3 == l15&3
    const int rq   = q ^ (l15 & 3);
    const int aoff = l15 * 32 + rq * 8;
    const int boff = (w * 64 + l15) * 32 + rq * 8;
    f32x4 acc[8][4] = {};
    const int NT = K >> 5;
    // prologue: stage tiles 0 and 1 (12 issues), wait tile 0 (6 newer outstanding)
#pragma unroll
    for (int pt = 0; pt < 2; pt++) {
        gl_lds16(Ag + pt * 32,       &lA[pt][tid * 8]);
        gl_lds16(Ag + r64 + pt * 32, &lA[pt][2048 + tid * 8]);
#pragma unroll
        for (int i = 0; i < 4; i++)
            gl_lds16(Bg + (size_t)i * r64 + pt * 32, &lB[pt][i * 2048 + tid * 8]);
    }
    asm volatile("s_waitcnt vmcnt(6)" ::: "memory");
    __builtin_amdgcn_sched_barrier(0);
    __builtin_amdgcn_s_barrier();
    int buf = 0, sbuf = 2, kk = 64;
    for (int t = 0; t < NT; t++) {
        if (t + 2 < NT) {                         // stage tile t+2
            gl_lds16(Ag + kk,       &lA[sbuf][tid * 8]);
            gl_lds16(Ag + r64 + kk, &lA[sbuf][2048 + tid * 8]);
#pragma unroll
            for (int i = 0; i < 4; i++)
                gl_lds16(Bg + (size_t)i * r64 + kk, &lB[sbuf][i * 2048 + tid * 8]);
        }
        bf16x8 afr[8], bfr[4];
#pragma unroll
        for (int nj = 0; nj < 4; nj++)
            bfr[nj] = *(const bf16x8*)&lB[buf][boff + nj * 512];
#pragma unroll
        for (int mi = 0; mi < 8; mi++)
            afr[mi] = *(const bf16x8*)&lA[buf][aoff + mi * 512];
        __builtin_amdgcn_s_barrier();
        __builtin_amdgcn_s_setprio(1);
#pragma unroll
        for (int mi = 0; mi < 8; mi++)
#pragma unroll
            for (int nj = 0; nj < 4; nj++)
                acc[mi][nj] = MFMA16(afr[mi], bfr[nj], acc[mi][nj]);
        __builtin_amdgcn_s_setprio(0);
        if (t + 2 < NT) {
            asm volatile("s_waitcnt vmcnt(6)" ::: "memory");   // tile t+1 landed
        } else if (t + 1 < NT) {
            asm volatile("s_waitcnt vmcnt(0)" ::: "memory");   // epilogue drain
        }
        __builtin_amdgcn_sched_barrier(0);
        __builtin_amdgcn_s_barrier();
        kk += 32;
        buf  = (buf  == 2) ? 0 : buf  + 1;
        sbuf = (sbuf == 2) ? 0 : sbuf + 1;
    }
    if (OUT_BF16) {
        bf16_t* C = (bf16_t*)Cout;
#pragma unroll
        for (int mi = 0; mi < 8; mi++)
#pragma unroll
            for (int nj = 0; nj < 4; nj++)
#pragma unroll
                for (int r = 0; r < 4; r++)
                    C[(size_t)(m0 + mi * 16 + q4 + r) * N + n0 + w * 64 + nj * 16 + l15] =
                        (bf16_t)acc[mi][nj][r];
    } else {
        float* C = (float*)Cout;
#pragma unroll
        for (int mi = 0; mi < 8; mi++)
#pragma unroll
            for (int nj = 0; nj < 4; nj++)
#pragma unroll
                for (int r = 0; r < 4; r++)
                    C[(size_t)(m0 + mi * 16 + q4 + r) * N + n0 + w * 64 + nj * 16 + l15] =
                        acc[mi][nj][r];
    }
}

// ---------------- kv_fused: proj -> vT_g (bf16 [dv][tok]) + Zc = v^T k per chunk ----------------
__global__ __launch_bounds__(64)
void kv_fused(const bf16_t* __restrict__ proj, bf16_t* __restrict__ vT_g,
              float* __restrict__ Zc) {
    const int idx = blockIdx.x;               // ((b*8+hk)*64 + c)
    const int c = idx & 63, hk = (idx >> 6) & 7, b = idx >> 9;
    const int tokBase = b * 4096 + c * 64;
    __shared__ float tk[64][65];
    __shared__ float tv[64][65];
    const int lane = threadIdx.x;
    const bf16_t* kg = proj + (size_t)tokBase * QKV + 2048 + hk * 64;
    const bf16_t* vg = proj + (size_t)tokBase * QKV + 2560 + hk * 64;
#pragma unroll
    for (int p = 0; p < 8; p++) {
        int tok = p * 8 + (lane >> 3);
        int d0  = (lane & 7) * 8;
        bf16x8 kv = *(const bf16x8*)&kg[(size_t)tok * QKV + d0];
        bf16x8 vv = *(const bf16x8*)&vg[(size_t)tok * QKV + d0];
#pragma unroll
        for (int e = 0; e < 8; e++) {
            tk[tok][d0 + e] = (float)kv[e];
            tv[tok][d0 + e] = (float)vv[e];
        }
    }
    __syncthreads();
#pragma unroll
    for (int p = 0; p < 8; p++) {
        int dv = p * 8 + (lane >> 3);
        int t0 = (lane & 7) * 8;
        bf16x8 o;
#pragma unroll
        for (int e = 0; e < 8; e++) o[e] = (bf16_t)tv[t0 + e][dv];
        *(bf16x8*)&vT_g[(size_t)idx * 4096 + dv * 64 + t0] = o;
    }
    const int l15 = lane & 15, q8 = (lane >> 4) * 8, q4 = (lane >> 4) * 4;
    f32x4 acc[4][4] = {};
#pragma unroll
    for (int ks = 0; ks < 2; ks++) {
        bf16x8 af[4], bf_[4];
#pragma unroll
        for (int mi = 0; mi < 4; mi++)
#pragma unroll
            for (int e = 0; e < 8; e++) af[mi][e] = (bf16_t)tv[ks * 32 + q8 + e][mi * 16 + l15];
#pragma unroll
        for (int nj = 0; nj < 4; nj++)
#pragma unroll
            for (int e = 0; e < 8; e++) bf_[nj][e] = (bf16_t)tk[ks * 32 + q8 + e][nj * 16 + l15];
#pragma unroll
        for (int mi = 0; mi < 4; mi++)
#pragma unroll
            for (int nj = 0; nj < 4; nj++)
                acc[mi][nj] = MFMA16(af[mi], bf_[nj], acc[mi][nj]);
    }
    float* zout = Zc + (size_t)idx * 4096;
#pragma unroll
    for (int mi = 0; mi < 4; mi++)
#pragma unroll
        for (int nj = 0; nj < 4; nj++)
#pragma unroll
            for (int r = 0; r < 4; r++)
                zout[(mi * 16 + q4 + r) * 64 + nj * 16 + l15] = acc[mi][nj][r];
}

// ---------------- prefix state (+S0), emit bf16 prefixes + final state ----------------
__global__ __launch_bounds__(256)
void prefix_state(const float* __restrict__ Zc, const float* __restrict__ S0,
                  bf16_t* __restrict__ Zp, float* __restrict__ SfOut) {
    const int slice = blockIdx.x & 15;
    const int bh = blockIdx.x >> 4;
    const int h = bh & 31, b = bh >> 5;
    const int hk = h >> 2;
    const int e = slice * 256 + threadIdx.x;      // e = dv*64 + dk
    const int dv = e >> 6, dk = e & 63;
    float acc = S0[(size_t)b * 131072 + h * 4096 + dk * 64 + dv];
    const float* zc = Zc + ((size_t)(b * 8 + hk) * 64) * 4096 + e;
    bf16_t* zp = Zp + ((size_t)(b * 32 + h) * 64) * 4096 + e;
#pragma unroll 4
    for (int c = 0; c < NCHUNK; c++) {
        zp[(size_t)c * 4096] = (bf16_t)acc;
        acc += zc[(size_t)c * 4096];
    }
    SfOut[(size_t)b * 131072 + h * 4096 + dk * 64 + dv] = acc;
}

// ---------------- attn: 4 GQA heads per block (one wave each) ----------------
__global__ __launch_bounds__(256)
void attn_chunk(const bf16_t* __restrict__ proj, const bf16_t* __restrict__ vT_g,
                const bf16_t* __restrict__ Zp, bf16_t* __restrict__ O) {
    const int idx = blockIdx.x;                 // (b*64 + c)*8 + hk
    const int hk = idx & 7, c = (idx >> 3) & 63, b = idx >> 9;
    const int g = threadIdx.x >> 6, lane = threadIdx.x & 63;
    const int h = hk * 4 + g;
    const int tokBase = b * 4096 + c * 64;
    __shared__ alignas(16) bf16_t zs_all[4][64 * ZSTR];
    bf16_t* zs = zs_all[g];
    const int l15 = lane & 15, q8 = (lane >> 4) * 8, q4 = (lane >> 4) * 4;
    const bf16_t* qrow  = proj + (size_t)tokBase * QKV + h * 64;
    const bf16_t* krow  = proj + (size_t)tokBase * QKV + 2048 + hk * 64;
    const bf16_t* zrow  = Zp + (((size_t)(b * 32 + h)) * 64 + c) * 4096;
    const bf16_t* vTrow = vT_g + ((size_t)(b * 8 + hk) * 64 + c) * 4096;

    bf16x8 qf[2][4];
#pragma unroll
    for (int ks = 0; ks < 2; ks++)
#pragma unroll
        for (int mi = 0; mi < 4; mi++)
            qf[ks][mi] = *(const bf16x8*)&qrow[(size_t)(mi * 16 + l15) * QKV + ks * 32 + q8];

    f32x4 oacc[4][4] = {};
#pragma unroll
    for (int ks = 0; ks < 2; ks++) {
        bf16x8 zf[4];
#pragma unroll
        for (int nj = 0; nj < 4; nj++) zf[nj] = *(const bf16x8*)&zrow[(nj * 16 + l15) * 64 + ks * 32 + q8];
#pragma unroll
        for (int mi = 0; mi < 4; mi++)
#pragma unroll
            for (int nj = 0; nj < 4; nj++)
                oacc[mi][nj] = MFMA16(qf[ks][mi], zf[nj], oacc[mi][nj]);
    }
    f32x4 sacc[4][4] = {};
#pragma unroll
    for (int ks = 0; ks < 2; ks++) {
        bf16x8 kf[4];
#pragma unroll
        for (int nj = 0; nj < 4; nj++) kf[nj] = *(const bf16x8*)&krow[(size_t)(nj * 16 + l15) * QKV + ks * 32 + q8];
#pragma unroll
        for (int mi = 0; mi < 4; mi++)
#pragma unroll
            for (int nj = 0; nj < 4; nj++)
                if (mi >= nj) sacc[mi][nj] = MFMA16(qf[ks][mi], kf[nj], sacc[mi][nj]);
    }
#pragma unroll
    for (int mi = 0; mi < 4; mi++)
#pragma unroll
        for (int nj = 0; nj < 4; nj++)
#pragma unroll
            for (int r = 0; r < 4; r++) {
                int ti = mi * 16 + q4 + r, tj = nj * 16 + l15;
                float v = (ti >= tj) ? sacc[mi][nj][r] : 0.0f;
                zs[ti * ZSTR + tj] = (bf16_t)v;
            }
    __syncthreads();
#pragma unroll
    for (int ks = 0; ks < 2; ks++) {
        bf16x8 sf[4], vf[4];
#pragma unroll
        for (int mi = 0; mi < 4; mi++) sf[mi] = *(const bf16x8*)&zs[(mi * 16 + l15) * ZSTR + ks * 32 + q8];
#pragma unroll
        for (int nj = 0; nj < 4; nj++) vf[nj] = *(const bf16x8*)&vTrow[(nj * 16 + l15) * 64 + ks * 32 + q8];
#pragma unroll
        for (int mi = 0; mi < 4; mi++)
#pragma unroll
            for (int nj = 0; nj < 4; nj++)
                oacc[mi][nj] = MFMA16(sf[mi], vf[nj], oacc[mi][nj]);
    }
    bf16_t* og = O + (size_t)tokBase * OUT_D + h * 64;
#pragma unroll
    for (int mi = 0; mi < 4; mi++)
#pragma unroll
        for (int nj = 0; nj < 4; nj++)
#pragma unroll
            for (int r = 0; r < 4; r++)
                og[(size_t)(mi * 16 + q4 + r) * OUT_D + nj * 16 + l15] = (bf16_t)oacc[mi][nj][r];
}

// ---------------- launcher ----------------
extern "C" void kernel_launch(void* const* d_in, const int* in_sizes, int n_in,
                              void* d_out, int out_size, void* d_ws, size_t ws_size,
                              hipStream_t stream) {
    const float* x     = (const float*)d_in[0];
    const float* S0    = (const float*)d_in[1];
    const float* W_in  = (const float*)d_in[2];
    const float* W_out = (const float*)d_in[3];

    char* ws = (char*)d_ws;
    bf16_t* xb    = (bf16_t*)(ws + 0);            // 33.5 MB; dead after GEMM1
    bf16_t* WinT  = (bf16_t*)(ws + 33554432);     // 12.6 MB; dead after GEMM1
    bf16_t* WoutT = (bf16_t*)(ws + 46137344);     // 8.4 MB; live until GEMM2
    bf16_t* proj  = (bf16_t*)(ws + 54525952);     // 50.3 MB
    float*  Zc    = (float*) (ws + 104857600);    // 16.8 MB
    bf16_t* Zp    = (bf16_t*)(ws + 121634816);    // 33.5 MB
    bf16_t* vT_g  = (bf16_t*)(ws + 0);            // 8.4 MB, overlays dead xb
    bf16_t* Ob    = (bf16_t*)(ws + 8388608);      // 33.5 MB, overlays dead xb/WinT

    float* outMain  = (float*)d_out;
    float* outState = (float*)d_out + (size_t)S_TOT * OUT_D;

    prep<<<16384 + 1536 + 1024, 256, 0, stream>>>(x, xb, W_in, WinT, W_out, WoutT);
    gemm_pipe<1><<<768, 256, 0, stream>>>(xb, WinT, proj, S_TOT, QKV, D_IN);
    kv_fused<<<1024, 64, 0, stream>>>(proj, vT_g, Zc);
    prefix_state<<<1024, 256, 0, stream>>>(Zc, S0, Zp, outState);
    attn_chunk<<<1024, 256, 0, stream>>>(proj, vT_g, Zp, Ob);
    gemm_pipe<0><<<512, 256, 0, stream>>>(Ob, WoutT, outMain, S_TOT, OUT_D, OUT_D);
}

// Round 2
// 381.845 us; speedup vs baseline: 1.1058x; 1.1058x over previous
//
#include <hip/hip_runtime.h>

typedef __bf16 bf16_t;
typedef __bf16 bf16x8 __attribute__((ext_vector_type(8)));
typedef __bf16 bf16x4 __attribute__((ext_vector_type(4)));
typedef float  f32x4  __attribute__((ext_vector_type(4)));

#define MFMA16(a,b,c) __builtin_amdgcn_mfma_f32_16x16x32_bf16((a),(b),(c),0,0,0)

__device__ __forceinline__ void gl_lds16(const void* g, void* l) {
    __builtin_amdgcn_global_load_lds(
        (__attribute__((address_space(1))) void*)(g),
        (__attribute__((address_space(3))) void*)(l),
        16, 0, 0);
}

// B=2 S=4096 D=2048 HQ=32 HK=HV=8 H=32 DK=DV=64 CHUNK=64 NC=64 QKV=3072 OUT=2048
static constexpr int S_TOT   = 8192;
static constexpr int D_IN    = 2048;
static constexpr int QKV     = 3072;
static constexpr int OUT_D   = 2048;
static constexpr int NCHUNK  = 64;
static constexpr int ZSTR    = 88;

// ---------------- prep: x->bf16 convert + both weight transposes, one launch ----------------
__global__ __launch_bounds__(256)
void prep(const float* __restrict__ x, bf16_t* __restrict__ xb,
          const float* __restrict__ W_in, bf16_t* __restrict__ WinT,
          const float* __restrict__ W_out, bf16_t* __restrict__ WoutT) {
    __shared__ float tile[64][65];
    const int bid = blockIdx.x;
    const int t   = threadIdx.x;
    if (bid < 16384) {
        int i = bid * 256 + t;
        f32x4 v = ((const f32x4*)x)[i];
        bf16x4 o;
        o[0] = (bf16_t)v[0]; o[1] = (bf16_t)v[1]; o[2] = (bf16_t)v[2]; o[3] = (bf16_t)v[3];
        ((bf16x4*)xb)[i] = o;
        return;
    }
    const float* in; bf16_t* out; int R, C, bx, by;
    int tb = bid - 16384;
    if (tb < 1536) { in = W_in;  out = WinT;  R = 2048; C = 3072; bx = tb % 48; by = tb / 48; }
    else { tb -= 1536; in = W_out; out = WoutT; R = 2048; C = 2048; bx = tb % 32; by = tb / 32; }
    const int r0 = by * 64, c0 = bx * 64;
#pragma unroll
    for (int p = 0; p < 4; p++) {
        int row = p * 16 + (t >> 4);
        int col = (t & 15) * 4;
        f32x4 v = *(const f32x4*)&in[(size_t)(r0 + row) * C + c0 + col];
        tile[row][col + 0] = v[0]; tile[row][col + 1] = v[1];
        tile[row][col + 2] = v[2]; tile[row][col + 3] = v[3];
    }
    __syncthreads();
#pragma unroll
    for (int p = 0; p < 4; p++) {
        int oc  = p * 16 + (t >> 4);
        int orr = (t & 15) * 4;
        bf16x4 v;
        v[0] = (bf16_t)tile[orr + 0][oc]; v[1] = (bf16_t)tile[orr + 1][oc];
        v[2] = (bf16_t)tile[orr + 2][oc]; v[3] = (bf16_t)tile[orr + 3][oc];
        *(bf16x4*)&out[(size_t)(c0 + oc) * R + r0 + orr] = v;
    }
}

// ---------------- GEMM: 256x256 tile, 8 waves, 4-phase/K-tile counted-vmcnt pipeline ----
// C[M][N] = A[M][K] * Bt[N][K]^T.  BK=64, 512 thr = 8 waves (4M x 2N), per-wave
// 64x128 output (acc[4][8]).  LDS = 2 bufs x (A 32KB + B 32KB) = 128 KB.
// Per phase j of tile T: {ds_read frags for quadrant nj={2j,2j+1} (A frags loaded
// once at j=0) | stage 1 half-tile of tile T+1 (2 x global_load_lds)} -> barrier ->
// lgkmcnt(0) -> setprio(1) + 16 MFMA + setprio(0) -> [vmcnt] -> barrier.
// Counted vmcnt (T3+T4): vmcnt(4) at end of phase 1, vmcnt(2) at end of phase 3;
// never 0 in the main loop (last tile drains with vmcnt(0) at phase 1).
// Staging order per tile: P0: A rows[0,128); P1: A rows[128,256); P2: B-X slabs
// {[0,64),[128,192)} (consumed by phases 0-1); P3: B-Y slabs {[64,128),[192,256)}
// (consumed by phases 2-3).  Race-freedom: the buffer staged during tile T's
// phases held tile T-1, fully consumed before T's first barrier.  Deadlines:
// A+B-X of T+1 confirmed by vmcnt(2)@T.P3 (2 newer loads = B-Y); B-Y of T+1
// confirmed by vmcnt(4)@(T+1).P1 (4 newer loads = A of T+2).
// XOR swizzle (chunk ^= row&7, proven 0-conflict at BK=64 in round 0) applied to
// the per-lane GLOBAL source so the global_load_lds dest stays linear; frag
// reads apply the same XOR.
template<int OUT_BF16>
__global__ __launch_bounds__(512, 2)
void gemm8p(const bf16_t* __restrict__ A, const bf16_t* __restrict__ Bt,
            void* __restrict__ Cout, int M, int N, int K, int nt) {
    __shared__ alignas(16) bf16_t lds[2][2][16384];   // [buf][A=0/B=1][256*64]
    const int tid = threadIdx.x;
    const int nwg = gridDim.x;
    int id = blockIdx.x;
    id = (id & 7) * (nwg >> 3) + (id >> 3);           // XCD swizzle (nwg % 8 == 0)
    const int n0 = (id % nt) * 256;                   // n-fast: XCD shares A panels
    const int m0 = (id / nt) * 256;
    const int w = tid >> 6, lane = tid & 63;
    const int l15 = lane & 15, q = lane >> 4, q4 = q * 4;
    const int wr = (w >> 1) * 64;                     // 4 M-waves
    const int wc = (w & 1) * 128;                     // 2 N-waves
    // staging source (per-thread, pre-swizzled k-chunk); dest stays linear
    const int trow = tid >> 3;                        // 0..63 within a 64-row slab
    const int tcc  = (tid & 7) ^ (trow & 7);
    const bf16_t* Ag = A  + (size_t)(m0 + trow) * K + tcc * 8;
    const bf16_t* Bg = Bt + (size_t)(n0 + trow) * K + tcc * 8;
    const size_t rK = (size_t)64 * K;
    // frag read offsets (elements), same XOR; row&7 == l15&7 for all frag rows
    int aoff[2], boff[2];
#pragma unroll
    for (int ks = 0; ks < 2; ks++) {
        aoff[ks] = (wr + l15) * 64 + (((ks * 4 + q) ^ (l15 & 7)) * 8);
        boff[ks] = (wc + l15) * 64 + (((ks * 4 + q) ^ (l15 & 7)) * 8);
    }
    f32x4 acc[4][8] = {};
    const int NT = K >> 6;
    // ---- prologue: stage tile 0 (A, B-X, B-Y order), wait all but B-Y ----
    {
        bf16_t* dA = &lds[0][0][0];
        bf16_t* dB = &lds[0][1][0];
        gl_lds16(Ag,            &dA[tid * 8]);            // A [0,64)
        gl_lds16(Ag + rK,       &dA[4096  + tid * 8]);    // A [64,128)
        gl_lds16(Ag + 2 * rK,   &dA[8192  + tid * 8]);    // A [128,192)
        gl_lds16(Ag + 3 * rK,   &dA[12288 + tid * 8]);    // A [192,256)
        gl_lds16(Bg,            &dB[tid * 8]);            // B [0,64)    (B-X)
        gl_lds16(Bg + 2 * rK,   &dB[8192  + tid * 8]);    // B [128,192) (B-X)
        gl_lds16(Bg + rK,       &dB[4096  + tid * 8]);    // B [64,128)  (B-Y)
        gl_lds16(Bg + 3 * rK,   &dB[12288 + tid * 8]);    // B [192,256) (B-Y)
    }
    asm volatile("s_waitcnt vmcnt(2)" ::: "memory");      // A + B-X landed
    __builtin_amdgcn_sched_barrier(0);
    __builtin_amdgcn_s_barrier();
    for (int t = 0; t < NT; t++) {
        const bf16_t* cA = &lds[t & 1][0][0];
        const bf16_t* cB = &lds[t & 1][1][0];
        bf16_t* sA = &lds[(t + 1) & 1][0][0];
        bf16_t* sB = &lds[(t + 1) & 1][1][0];
        const size_t kk = (size_t)(t + 1) * 64;
        const bool st = (t + 1 < NT);
        bf16x8 af[4][2];
#pragma unroll
        for (int j = 0; j < 4; j++) {
            bf16x8 bfr[2][2];
            if (j == 0) {
#pragma unroll
                for (int mi = 0; mi < 4; mi++)
#pragma unroll
                    for (int ks = 0; ks < 2; ks++)
                        af[mi][ks] = *(const bf16x8*)&cA[aoff[ks] + mi * 1024];
            }
#pragma unroll
            for (int nj = 0; nj < 2; nj++)
#pragma unroll
                for (int ks = 0; ks < 2; ks++)
                    bfr[nj][ks] = *(const bf16x8*)&cB[boff[ks] + (2 * j + nj) * 1024];
            if (st) {
                if (j == 0) {
                    gl_lds16(Ag + kk,            &sA[tid * 8]);
                    gl_lds16(Ag + rK + kk,       &sA[4096  + tid * 8]);
                } else if (j == 1) {
                    gl_lds16(Ag + 2 * rK + kk,   &sA[8192  + tid * 8]);
                    gl_lds16(Ag + 3 * rK + kk,   &sA[12288 + tid * 8]);
                } else if (j == 2) {
                    gl_lds16(Bg + kk,            &sB[tid * 8]);
                    gl_lds16(Bg + 2 * rK + kk,   &sB[8192  + tid * 8]);
                } else {
                    gl_lds16(Bg + rK + kk,       &sB[4096  + tid * 8]);
                    gl_lds16(Bg + 3 * rK + kk,   &sB[12288 + tid * 8]);
                }
            }
            __builtin_amdgcn_sched_barrier(0);
            __builtin_amdgcn_s_barrier();
            asm volatile("s_waitcnt lgkmcnt(0)" ::: "memory");
            __builtin_amdgcn_sched_barrier(0);
            __builtin_amdgcn_s_setprio(1);
#pragma unroll
            for (int mi = 0; mi < 4; mi++)
#pragma unroll
                for (int nj = 0; nj < 2; nj++)
#pragma unroll
                    for (int ks = 0; ks < 2; ks++)
                        acc[mi][2 * j + nj] = MFMA16(af[mi][ks], bfr[nj][ks], acc[mi][2 * j + nj]);
            __builtin_amdgcn_s_setprio(0);
            if (j == 1) {
                if (st) asm volatile("s_waitcnt vmcnt(4)" ::: "memory"); // B-Y(t) landed
                else    asm volatile("s_waitcnt vmcnt(0)" ::: "memory"); // last tile drain
                __builtin_amdgcn_sched_barrier(0);
            } else if (j == 3) {
                if (st) {
                    asm volatile("s_waitcnt vmcnt(2)" ::: "memory");     // A+B-X(t+1) landed
                    __builtin_amdgcn_sched_barrier(0);
                }
            }
            __builtin_amdgcn_s_barrier();
        }
    }
    if (OUT_BF16) {
        bf16_t* C = (bf16_t*)Cout;
#pragma unroll
        for (int mi = 0; mi < 4; mi++)
#pragma unroll
            for (int nj = 0; nj < 8; nj++)
#pragma unroll
                for (int r = 0; r < 4; r++)
                    C[(size_t)(m0 + wr + mi * 16 + q4 + r) * N + n0 + wc + nj * 16 + l15] =
                        (bf16_t)acc[mi][nj][r];
    } else {
        float* C = (float*)Cout;
#pragma unroll
        for (int mi = 0; mi < 4; mi++)
#pragma unroll
            for (int nj = 0; nj < 8; nj++)
#pragma unroll
                for (int r = 0; r < 4; r++)
                    C[(size_t)(m0 + wr + mi * 16 + q4 + r) * N + n0 + wc + nj * 16 + l15] =
                        acc[mi][nj][r];
    }
}

// ---------------- kv_fused: proj -> vT_g (bf16 [dv][tok]) + Zc = v^T k per chunk ----------------
__global__ __launch_bounds__(64)
void kv_fused(const bf16_t* __restrict__ proj, bf16_t* __restrict__ vT_g,
              float* __restrict__ Zc) {
    const int idx = blockIdx.x;               // ((b*8+hk)*64 + c)
    const int c = idx & 63, hk = (idx >> 6) & 7, b = idx >> 9;
    const int tokBase = b * 4096 + c * 64;
    __shared__ float tk[64][65];
    __shared__ float tv[64][65];
    const int lane = threadIdx.x;
    const bf16_t* kg = proj + (size_t)tokBase * QKV + 2048 + hk * 64;
    const bf16_t* vg = proj + (size_t)tokBase * QKV + 2560 + hk * 64;
#pragma unroll
    for (int p = 0; p < 8; p++) {
        int tok = p * 8 + (lane >> 3);
        int d0  = (lane & 7) * 8;
        bf16x8 kv = *(const bf16x8*)&kg[(size_t)tok * QKV + d0];
        bf16x8 vv = *(const bf16x8*)&vg[(size_t)tok * QKV + d0];
#pragma unroll
        for (int e = 0; e < 8; e++) {
            tk[tok][d0 + e] = (float)kv[e];
            tv[tok][d0 + e] = (float)vv[e];
        }
    }
    __syncthreads();
#pragma unroll
    for (int p = 0; p < 8; p++) {
        int dv = p * 8 + (lane >> 3);
        int t0 = (lane & 7) * 8;
        bf16x8 o;
#pragma unroll
        for (int e = 0; e < 8; e++) o[e] = (bf16_t)tv[t0 + e][dv];
        *(bf16x8*)&vT_g[(size_t)idx * 4096 + dv * 64 + t0] = o;
    }
    const int l15 = lane & 15, q8 = (lane >> 4) * 8, q4 = (lane >> 4) * 4;
    f32x4 acc[4][4] = {};
#pragma unroll
    for (int ks = 0; ks < 2; ks++) {
        bf16x8 af[4], bf_[4];
#pragma unroll
        for (int mi = 0; mi < 4; mi++)
#pragma unroll
            for (int e = 0; e < 8; e++) af[mi][e] = (bf16_t)tv[ks * 32 + q8 + e][mi * 16 + l15];
#pragma unroll
        for (int nj = 0; nj < 4; nj++)
#pragma unroll
            for (int e = 0; e < 8; e++) bf_[nj][e] = (bf16_t)tk[ks * 32 + q8 + e][nj * 16 + l15];
#pragma unroll
        for (int mi = 0; mi < 4; mi++)
#pragma unroll
            for (int nj = 0; nj < 4; nj++)
                acc[mi][nj] = MFMA16(af[mi], bf_[nj], acc[mi][nj]);
    }
    float* zout = Zc + (size_t)idx * 4096;
#pragma unroll
    for (int mi = 0; mi < 4; mi++)
#pragma unroll
        for (int nj = 0; nj < 4; nj++)
#pragma unroll
            for (int r = 0; r < 4; r++)
                zout[(mi * 16 + q4 + r) * 64 + nj * 16 + l15] = acc[mi][nj][r];
}

// ---------------- prefix state (+S0), emit bf16 prefixes + final state ----------------
__global__ __launch_bounds__(256)
void prefix_state(const float* __restrict__ Zc, const float* __restrict__ S0,
                  bf16_t* __restrict__ Zp, float* __restrict__ SfOut) {
    const int slice = blockIdx.x & 15;
    const int bh = blockIdx.x >> 4;
    const int h = bh & 31, b = bh >> 5;
    const int hk = h >> 2;
    const int e = slice * 256 + threadIdx.x;      // e = dv*64 + dk
    const int dv = e >> 6, dk = e & 63;
    float acc = S0[(size_t)b * 131072 + h * 4096 + dk * 64 + dv];
    const float* zc = Zc + ((size_t)(b * 8 + hk) * 64) * 4096 + e;
    bf16_t* zp = Zp + ((size_t)(b * 32 + h) * 64) * 4096 + e;
#pragma unroll 4
    for (int c = 0; c < NCHUNK; c++) {
        zp[(size_t)c * 4096] = (bf16_t)acc;
        acc += zc[(size_t)c * 4096];
    }
    SfOut[(size_t)b * 131072 + h * 4096 + dk * 64 + dv] = acc;
}

// ---------------- attn: 4 GQA heads per block (one wave each) ----------------
__global__ __launch_bounds__(256)
void attn_chunk(const bf16_t* __restrict__ proj, const bf16_t* __restrict__ vT_g,
                const bf16_t* __restrict__ Zp, bf16_t* __restrict__ O) {
    const int idx = blockIdx.x;                 // (b*64 + c)*8 + hk
    const int hk = idx & 7, c = (idx >> 3) & 63, b = idx >> 9;
    const int g = threadIdx.x >> 6, lane = threadIdx.x & 63;
    const int h = hk * 4 + g;
    const int tokBase = b * 4096 + c * 64;
    __shared__ alignas(16) bf16_t zs_all[4][64 * ZSTR];
    bf16_t* zs = zs_all[g];
    const int l15 = lane & 15, q8 = (lane >> 4) * 8, q4 = (lane >> 4) * 4;
    const bf16_t* qrow  = proj + (size_t)tokBase * QKV + h * 64;
    const bf16_t* krow  = proj + (size_t)tokBase * QKV + 2048 + hk * 64;
    const bf16_t* zrow  = Zp + (((size_t)(b * 32 + h)) * 64 + c) * 4096;
    const bf16_t* vTrow = vT_g + ((size_t)(b * 8 + hk) * 64 + c) * 4096;

    bf16x8 qf[2][4];
#pragma unroll
    for (int ks = 0; ks < 2; ks++)
#pragma unroll
        for (int mi = 0; mi < 4; mi++)
            qf[ks][mi] = *(const bf16x8*)&qrow[(size_t)(mi * 16 + l15) * QKV + ks * 32 + q8];

    f32x4 oacc[4][4] = {};
#pragma unroll
    for (int ks = 0; ks < 2; ks++) {
        bf16x8 zf[4];
#pragma unroll
        for (int nj = 0; nj < 4; nj++) zf[nj] = *(const bf16x8*)&zrow[(nj * 16 + l15) * 64 + ks * 32 + q8];
#pragma unroll
        for (int mi = 0; mi < 4; mi++)
#pragma unroll
            for (int nj = 0; nj < 4; nj++)
                oacc[mi][nj] = MFMA16(qf[ks][mi], zf[nj], oacc[mi][nj]);
    }
    f32x4 sacc[4][4] = {};
#pragma unroll
    for (int ks = 0; ks < 2; ks++) {
        bf16x8 kf[4];
#pragma unroll
        for (int nj = 0; nj < 4; nj++) kf[nj] = *(const bf16x8*)&krow[(size_t)(nj * 16 + l15) * QKV + ks * 32 + q8];
#pragma unroll
        for (int mi = 0; mi < 4; mi++)
#pragma unroll
            for (int nj = 0; nj < 4; nj++)
                if (mi >= nj) sacc[mi][nj] = MFMA16(qf[ks][mi], kf[nj], sacc[mi][nj]);
    }
#pragma unroll
    for (int mi = 0; mi < 4; mi++)
#pragma unroll
        for (int nj = 0; nj < 4; nj++)
#pragma unroll
            for (int r = 0; r < 4; r++) {
                int ti = mi * 16 + q4 + r, tj = nj * 16 + l15;
                float v = (ti >= tj) ? sacc[mi][nj][r] : 0.0f;
                zs[ti * ZSTR + tj] = (bf16_t)v;
            }
    __syncthreads();
#pragma unroll
    for (int ks = 0; ks < 2; ks++) {
        bf16x8 sf[4], vf[4];
#pragma unroll
        for (int mi = 0; mi < 4; mi++) sf[mi] = *(const bf16x8*)&zs[(mi * 16 + l15) * ZSTR + ks * 32 + q8];
#pragma unroll
        for (int nj = 0; nj < 4; nj++) vf[nj] = *(const bf16x8*)&vTrow[(nj * 16 + l15) * 64 + ks * 32 + q8];
#pragma unroll
        for (int mi = 0; mi < 4; mi++)
#pragma unroll
            for (int nj = 0; nj < 4; nj++)
                oacc[mi][nj] = MFMA16(sf[mi], vf[nj], oacc[mi][nj]);
    }
    bf16_t* og = O + (size_t)tokBase * OUT_D + h * 64;
#pragma unroll
    for (int mi = 0; mi < 4; mi++)
#pragma unroll
        for (int nj = 0; nj < 4; nj++)
#pragma unroll
            for (int r = 0; r < 4; r++)
                og[(size_t)(mi * 16 + q4 + r) * OUT_D + nj * 16 + l15] = (bf16_t)oacc[mi][nj][r];
}

// ---------------- launcher ----------------
extern "C" void kernel_launch(void* const* d_in, const int* in_sizes, int n_in,
                              void* d_out, int out_size, void* d_ws, size_t ws_size,
                              hipStream_t stream) {
    const float* x     = (const float*)d_in[0];
    const float* S0    = (const float*)d_in[1];
    const float* W_in  = (const float*)d_in[2];
    const float* W_out = (const float*)d_in[3];

    char* ws = (char*)d_ws;
    bf16_t* xb    = (bf16_t*)(ws + 0);            // 33.5 MB; dead after GEMM1
    bf16_t* WinT  = (bf16_t*)(ws + 33554432);     // 12.6 MB; dead after GEMM1
    bf16_t* WoutT = (bf16_t*)(ws + 46137344);     // 8.4 MB; live until GEMM2
    bf16_t* proj  = (bf16_t*)(ws + 54525952);     // 50.3 MB
    float*  Zc    = (float*) (ws + 104857600);    // 16.8 MB
    bf16_t* Zp    = (bf16_t*)(ws + 121634816);    // 33.5 MB
    bf16_t* vT_g  = (bf16_t*)(ws + 0);            // 8.4 MB, overlays dead xb
    bf16_t* Ob    = (bf16_t*)(ws + 8388608);      // 33.5 MB, overlays dead xb/WinT

    float* outMain  = (float*)d_out;
    float* outState = (float*)d_out + (size_t)S_TOT * OUT_D;

    prep<<<16384 + 1536 + 1024, 256, 0, stream>>>(x, xb, W_in, WinT, W_out, WoutT);
    gemm8p<1><<<384, 512, 0, stream>>>(xb, WinT, proj, S_TOT, QKV, D_IN, 12);
    kv_fused<<<1024, 64, 0, stream>>>(proj, vT_g, Zc);
    prefix_state<<<1024, 256, 0, stream>>>(Zc, S0, Zp, outState);
    attn_chunk<<<1024, 256, 0, stream>>>(proj, vT_g, Zp, Ob);
    gemm8p<0><<<256, 512, 0, stream>>>(Ob, WoutT, outMain, S_TOT, OUT_D, OUT_D, 8);
}

// Round 3
// 367.043 us; speedup vs baseline: 1.1504x; 1.0403x over previous
//
#include <hip/hip_runtime.h>

typedef __bf16 bf16_t;
typedef __bf16 bf16x8 __attribute__((ext_vector_type(8)));
typedef __bf16 bf16x4 __attribute__((ext_vector_type(4)));
typedef float  f32x4  __attribute__((ext_vector_type(4)));

#define MFMA16(a,b,c) __builtin_amdgcn_mfma_f32_16x16x32_bf16((a),(b),(c),0,0,0)

__device__ __forceinline__ void gl_lds16(const void* g, void* l) {
    __builtin_amdgcn_global_load_lds(
        (__attribute__((address_space(1))) void*)(g),
        (__attribute__((address_space(3))) void*)(l),
        16, 0, 0);
}

// B=2 S=4096 D=2048 HQ=32 HK=HV=8 H=32 DK=DV=64 CHUNK=64 NC=64 QKV=3072 OUT=2048
static constexpr int S_TOT   = 8192;
static constexpr int D_IN    = 2048;
static constexpr int QKV     = 3072;
static constexpr int OUT_D   = 2048;
static constexpr int NCHUNK  = 64;
static constexpr int ZSTR    = 88;

// ---------------- prep: x->bf16 convert + both weight transposes, one launch ----------------
__global__ __launch_bounds__(256)
void prep(const float* __restrict__ x, bf16_t* __restrict__ xb,
          const float* __restrict__ W_in, bf16_t* __restrict__ WinT,
          const float* __restrict__ W_out, bf16_t* __restrict__ WoutT) {
    __shared__ float tile[64][65];
    const int bid = blockIdx.x;
    const int t   = threadIdx.x;
    if (bid < 16384) {
        int i = bid * 256 + t;
        f32x4 v = ((const f32x4*)x)[i];
        bf16x4 o;
        o[0] = (bf16_t)v[0]; o[1] = (bf16_t)v[1]; o[2] = (bf16_t)v[2]; o[3] = (bf16_t)v[3];
        ((bf16x4*)xb)[i] = o;
        return;
    }
    const float* in; bf16_t* out; int R, C, bx, by;
    int tb = bid - 16384;
    if (tb < 1536) { in = W_in;  out = WinT;  R = 2048; C = 3072; bx = tb % 48; by = tb / 48; }
    else { tb -= 1536; in = W_out; out = WoutT; R = 2048; C = 2048; bx = tb % 32; by = tb / 32; }
    const int r0 = by * 64, c0 = bx * 64;
#pragma unroll
    for (int p = 0; p < 4; p++) {
        int row = p * 16 + (t >> 4);
        int col = (t & 15) * 4;
        f32x4 v = *(const f32x4*)&in[(size_t)(r0 + row) * C + c0 + col];
        tile[row][col + 0] = v[0]; tile[row][col + 1] = v[1];
        tile[row][col + 2] = v[2]; tile[row][col + 3] = v[3];
    }
    __syncthreads();
#pragma unroll
    for (int p = 0; p < 4; p++) {
        int oc  = p * 16 + (t >> 4);
        int orr = (t & 15) * 4;
        bf16x4 v;
        v[0] = (bf16_t)tile[orr + 0][oc]; v[1] = (bf16_t)tile[orr + 1][oc];
        v[2] = (bf16_t)tile[orr + 2][oc]; v[3] = (bf16_t)tile[orr + 3][oc];
        *(bf16x4*)&out[(size_t)(c0 + oc) * R + r0 + orr] = v;
    }
}

// ---------------- GEMM: 128x128 tile, double-buffered, ONE barrier per K-tile ----------------
// C[M][N] = A[M][K]*Bt[N][K]^T.  BK=64, 256 thr = 4 waves (2Mx2N), wave 64x64,
// acc[4][4].  LDS 2 bufs x 32KB = 64KB -> 2 blocks/CU (cross-block overlap).
// Per tile t: issue 8 global_load_lds for t+1 (other buf); issue 16 frag
// ds_read_b128 for t; 32 MFMA (compiler inserts counted lgkm waits and
// interleaves reads under MFMA); s_waitcnt vmcnt(0) (satisfied early: the
// loads were issued a full tile (~1300 cyc) before, > HBM latency); raw
// s_barrier.  Race-freedom: reads of buf[t&1] happen only after the
// end-of-(t-1) barrier, which each wave crosses only after its own vmcnt(0)
// => all waves' tile-t loads landed.  Staging t+1 targets the buffer that
// held t-1, fully consumed before that same barrier.
// Swizzle identical to round-0 (proven 0-conflict, numerics proven): source
// chunk tcc = (tid&7)^(trow&7) pre-applied to the per-lane GLOBAL address
// (dest stays linear for global_load_lds); frag reads use cc = (ks*4+q)^(l15&7).
template<int OUT_BF16>
__global__ __launch_bounds__(256, 2)
void gemm_p2(const bf16_t* __restrict__ A, const bf16_t* __restrict__ Bt,
             void* __restrict__ Cout, int M, int N, int K, int ntile) {
    __shared__ alignas(16) bf16_t lds[2][2][8192];   // [buf][A=0/B=1][128*64]
    const int tid = threadIdx.x;
    const int nwg = gridDim.x;
    int id = blockIdx.x;
    id = (id & 7) * (nwg >> 3) + (id >> 3);          // XCD swizzle (nwg % 8 == 0)
    const int n0 = (id % ntile) * 128;               // n-fast within an XCD chunk
    const int m0 = (id / ntile) * 128;
    const int w = tid >> 6, lane = tid & 63;
    const int l15 = lane & 15, q = lane >> 4, q4 = q * 4;
    const int wr = (w >> 1) * 64, wc = (w & 1) * 64;
    const int trow = tid >> 3;                       // 0..31
    const int tcc  = (tid & 7) ^ (trow & 7);         // swizzled source k-chunk
    const bf16_t* Ag = A  + (size_t)(m0 + trow) * K + tcc * 8;
    const bf16_t* Bg = Bt + (size_t)(n0 + trow) * K + tcc * 8;
    const size_t r32 = (size_t)32 * K;
    int cc[2];
    cc[0] = (q ^ (l15 & 7)) * 8;                     // frag k-chunk, ks=0
    cc[1] = ((4 + q) ^ (l15 & 7)) * 8;               // frag k-chunk, ks=1
    f32x4 acc[4][4] = {};
    const int NT = K >> 6;
    // prologue: stage tile 0 into buf 0 (cold wait, once)
#pragma unroll
    for (int j = 0; j < 4; j++) {
        gl_lds16(Ag + j * r32, &lds[0][0][j * 2048 + tid * 8]);
        gl_lds16(Bg + j * r32, &lds[0][1][j * 2048 + tid * 8]);
    }
    asm volatile("s_waitcnt vmcnt(0)" ::: "memory");
    __builtin_amdgcn_sched_barrier(0);
    __builtin_amdgcn_s_barrier();
    __builtin_amdgcn_sched_barrier(0);
    for (int t = 0; t < NT; t++) {
        const int cb = t & 1;
        if (t + 1 < NT) {                            // stage tile t+1 -> other buf
            const size_t kk = (size_t)(t + 1) * 64;
#pragma unroll
            for (int j = 0; j < 4; j++) {
                gl_lds16(Ag + j * r32 + kk, &lds[cb ^ 1][0][j * 2048 + tid * 8]);
                gl_lds16(Bg + j * r32 + kk, &lds[cb ^ 1][1][j * 2048 + tid * 8]);
            }
        }
        bf16x8 af[4][2], bfr[4][2];
#pragma unroll
        for (int mi = 0; mi < 4; mi++)
#pragma unroll
            for (int ks = 0; ks < 2; ks++)
                af[mi][ks] = *(const bf16x8*)&lds[cb][0][(wr + mi * 16 + l15) * 64 + cc[ks]];
#pragma unroll
        for (int nj = 0; nj < 4; nj++)
#pragma unroll
            for (int ks = 0; ks < 2; ks++)
                bfr[nj][ks] = *(const bf16x8*)&lds[cb][1][(wc + nj * 16 + l15) * 64 + cc[ks]];
        __builtin_amdgcn_s_setprio(1);
#pragma unroll
        for (int mi = 0; mi < 4; mi++)
#pragma unroll
            for (int nj = 0; nj < 4; nj++)
#pragma unroll
                for (int ks = 0; ks < 2; ks++)
                    acc[mi][nj] = MFMA16(af[mi][ks], bfr[nj][ks], acc[mi][nj]);
        __builtin_amdgcn_s_setprio(0);
        if (t + 1 < NT) {
            __builtin_amdgcn_sched_barrier(0);
            asm volatile("s_waitcnt vmcnt(0)" ::: "memory");   // t+1 landed (issued ~1 tile ago)
            __builtin_amdgcn_sched_barrier(0);
            __builtin_amdgcn_s_barrier();
            __builtin_amdgcn_sched_barrier(0);
        }
    }
    if (OUT_BF16) {
        bf16_t* C = (bf16_t*)Cout;
#pragma unroll
        for (int mi = 0; mi < 4; mi++)
#pragma unroll
            for (int nj = 0; nj < 4; nj++)
#pragma unroll
                for (int r = 0; r < 4; r++)
                    C[(size_t)(m0 + wr + mi * 16 + q4 + r) * N + n0 + wc + nj * 16 + l15] =
                        (bf16_t)acc[mi][nj][r];
    } else {
        float* C = (float*)Cout;
#pragma unroll
        for (int mi = 0; mi < 4; mi++)
#pragma unroll
            for (int nj = 0; nj < 4; nj++)
#pragma unroll
                for (int r = 0; r < 4; r++)
                    C[(size_t)(m0 + wr + mi * 16 + q4 + r) * N + n0 + wc + nj * 16 + l15] =
                        acc[mi][nj][r];
    }
}

// ---------------- kv_fused: proj -> vT_g (bf16 [dv][tok]) + Zc = v^T k per chunk ----------------
__global__ __launch_bounds__(64)
void kv_fused(const bf16_t* __restrict__ proj, bf16_t* __restrict__ vT_g,
              float* __restrict__ Zc) {
    const int idx = blockIdx.x;               // ((b*8+hk)*64 + c)
    const int c = idx & 63, hk = (idx >> 6) & 7, b = idx >> 9;
    const int tokBase = b * 4096 + c * 64;
    __shared__ float tk[64][65];
    __shared__ float tv[64][65];
    const int lane = threadIdx.x;
    const bf16_t* kg = proj + (size_t)tokBase * QKV + 2048 + hk * 64;
    const bf16_t* vg = proj + (size_t)tokBase * QKV + 2560 + hk * 64;
#pragma unroll
    for (int p = 0; p < 8; p++) {
        int tok = p * 8 + (lane >> 3);
        int d0  = (lane & 7) * 8;
        bf16x8 kv = *(const bf16x8*)&kg[(size_t)tok * QKV + d0];
        bf16x8 vv = *(const bf16x8*)&vg[(size_t)tok * QKV + d0];
#pragma unroll
        for (int e = 0; e < 8; e++) {
            tk[tok][d0 + e] = (float)kv[e];
            tv[tok][d0 + e] = (float)vv[e];
        }
    }
    __syncthreads();
#pragma unroll
    for (int p = 0; p < 8; p++) {
        int dv = p * 8 + (lane >> 3);
        int t0 = (lane & 7) * 8;
        bf16x8 o;
#pragma unroll
        for (int e = 0; e < 8; e++) o[e] = (bf16_t)tv[t0 + e][dv];
        *(bf16x8*)&vT_g[(size_t)idx * 4096 + dv * 64 + t0] = o;
    }
    const int l15 = lane & 15, q8 = (lane >> 4) * 8, q4 = (lane >> 4) * 4;
    f32x4 acc[4][4] = {};
#pragma unroll
    for (int ks = 0; ks < 2; ks++) {
        bf16x8 af[4], bf_[4];
#pragma unroll
        for (int mi = 0; mi < 4; mi++)
#pragma unroll
            for (int e = 0; e < 8; e++) af[mi][e] = (bf16_t)tv[ks * 32 + q8 + e][mi * 16 + l15];
#pragma unroll
        for (int nj = 0; nj < 4; nj++)
#pragma unroll
            for (int e = 0; e < 8; e++) bf_[nj][e] = (bf16_t)tk[ks * 32 + q8 + e][nj * 16 + l15];
#pragma unroll
        for (int mi = 0; mi < 4; mi++)
#pragma unroll
            for (int nj = 0; nj < 4; nj++)
                acc[mi][nj] = MFMA16(af[mi], bf_[nj], acc[mi][nj]);
    }
    float* zout = Zc + (size_t)idx * 4096;
#pragma unroll
    for (int mi = 0; mi < 4; mi++)
#pragma unroll
        for (int nj = 0; nj < 4; nj++)
#pragma unroll
            for (int r = 0; r < 4; r++)
                zout[(mi * 16 + q4 + r) * 64 + nj * 16 + l15] = acc[mi][nj][r];
}

// ---------------- prefix state (+S0), emit bf16 prefixes + final state ----------------
__global__ __launch_bounds__(256)
void prefix_state(const float* __restrict__ Zc, const float* __restrict__ S0,
                  bf16_t* __restrict__ Zp, float* __restrict__ SfOut) {
    const int slice = blockIdx.x & 15;
    const int bh = blockIdx.x >> 4;
    const int h = bh & 31, b = bh >> 5;
    const int hk = h >> 2;
    const int e = slice * 256 + threadIdx.x;      // e = dv*64 + dk
    const int dv = e >> 6, dk = e & 63;
    float acc = S0[(size_t)b * 131072 + h * 4096 + dk * 64 + dv];
    const float* zc = Zc + ((size_t)(b * 8 + hk) * 64) * 4096 + e;
    bf16_t* zp = Zp + ((size_t)(b * 32 + h) * 64) * 4096 + e;
#pragma unroll 4
    for (int c = 0; c < NCHUNK; c++) {
        zp[(size_t)c * 4096] = (bf16_t)acc;
        acc += zc[(size_t)c * 4096];
    }
    SfOut[(size_t)b * 131072 + h * 4096 + dk * 64 + dv] = acc;
}

// ---------------- attn: 4 GQA heads per block (one wave each) ----------------
__global__ __launch_bounds__(256)
void attn_chunk(const bf16_t* __restrict__ proj, const bf16_t* __restrict__ vT_g,
                const bf16_t* __restrict__ Zp, bf16_t* __restrict__ O) {
    const int idx = blockIdx.x;                 // (b*64 + c)*8 + hk
    const int hk = idx & 7, c = (idx >> 3) & 63, b = idx >> 9;
    const int g = threadIdx.x >> 6, lane = threadIdx.x & 63;
    const int h = hk * 4 + g;
    const int tokBase = b * 4096 + c * 64;
    __shared__ alignas(16) bf16_t zs_all[4][64 * ZSTR];
    bf16_t* zs = zs_all[g];
    const int l15 = lane & 15, q8 = (lane >> 4) * 8, q4 = (lane >> 4) * 4;
    const bf16_t* qrow  = proj + (size_t)tokBase * QKV + h * 64;
    const bf16_t* krow  = proj + (size_t)tokBase * QKV + 2048 + hk * 64;
    const bf16_t* zrow  = Zp + (((size_t)(b * 32 + h)) * 64 + c) * 4096;
    const bf16_t* vTrow = vT_g + ((size_t)(b * 8 + hk) * 64 + c) * 4096;

    bf16x8 qf[2][4];
#pragma unroll
    for (int ks = 0; ks < 2; ks++)
#pragma unroll
        for (int mi = 0; mi < 4; mi++)
            qf[ks][mi] = *(const bf16x8*)&qrow[(size_t)(mi * 16 + l15) * QKV + ks * 32 + q8];

    f32x4 oacc[4][4] = {};
#pragma unroll
    for (int ks = 0; ks < 2; ks++) {
        bf16x8 zf[4];
#pragma unroll
        for (int nj = 0; nj < 4; nj++) zf[nj] = *(const bf16x8*)&zrow[(nj * 16 + l15) * 64 + ks * 32 + q8];
#pragma unroll
        for (int mi = 0; mi < 4; mi++)
#pragma unroll
            for (int nj = 0; nj < 4; nj++)
                oacc[mi][nj] = MFMA16(qf[ks][mi], zf[nj], oacc[mi][nj]);
    }
    f32x4 sacc[4][4] = {};
#pragma unroll
    for (int ks = 0; ks < 2; ks++) {
        bf16x8 kf[4];
#pragma unroll
        for (int nj = 0; nj < 4; nj++) kf[nj] = *(const bf16x8*)&krow[(size_t)(nj * 16 + l15) * QKV + ks * 32 + q8];
#pragma unroll
        for (int mi = 0; mi < 4; mi++)
#pragma unroll
            for (int nj = 0; nj < 4; nj++)
                if (mi >= nj) sacc[mi][nj] = MFMA16(qf[ks][mi], kf[nj], sacc[mi][nj]);
    }
#pragma unroll
    for (int mi = 0; mi < 4; mi++)
#pragma unroll
        for (int nj = 0; nj < 4; nj++)
#pragma unroll
            for (int r = 0; r < 4; r++) {
                int ti = mi * 16 + q4 + r, tj = nj * 16 + l15;
                float v = (ti >= tj) ? sacc[mi][nj][r] : 0.0f;
                zs[ti * ZSTR + tj] = (bf16_t)v;
            }
    __syncthreads();
#pragma unroll
    for (int ks = 0; ks < 2; ks++) {
        bf16x8 sf[4], vf[4];
#pragma unroll
        for (int mi = 0; mi < 4; mi++) sf[mi] = *(const bf16x8*)&zs[(mi * 16 + l15) * ZSTR + ks * 32 + q8];
#pragma unroll
        for (int nj = 0; nj < 4; nj++) vf[nj] = *(const bf16x8*)&vTrow[(nj * 16 + l15) * 64 + ks * 32 + q8];
#pragma unroll
        for (int mi = 0; mi < 4; mi++)
#pragma unroll
            for (int nj = 0; nj < 4; nj++)
                oacc[mi][nj] = MFMA16(sf[mi], vf[nj], oacc[mi][nj]);
    }
    bf16_t* og = O + (size_t)tokBase * OUT_D + h * 64;
#pragma unroll
    for (int mi = 0; mi < 4; mi++)
#pragma unroll
        for (int nj = 0; nj < 4; nj++)
#pragma unroll
            for (int r = 0; r < 4; r++)
                og[(size_t)(mi * 16 + q4 + r) * OUT_D + nj * 16 + l15] = (bf16_t)oacc[mi][nj][r];
}

// ---------------- launcher ----------------
extern "C" void kernel_launch(void* const* d_in, const int* in_sizes, int n_in,
                              void* d_out, int out_size, void* d_ws, size_t ws_size,
                              hipStream_t stream) {
    const float* x     = (const float*)d_in[0];
    const float* S0    = (const float*)d_in[1];
    const float* W_in  = (const float*)d_in[2];
    const float* W_out = (const float*)d_in[3];

    char* ws = (char*)d_ws;
    bf16_t* xb    = (bf16_t*)(ws + 0);            // 33.5 MB; dead after GEMM1
    bf16_t* WinT  = (bf16_t*)(ws + 33554432);     // 12.6 MB; dead after GEMM1
    bf16_t* WoutT = (bf16_t*)(ws + 46137344);     // 8.4 MB; live until GEMM2
    bf16_t* proj  = (bf16_t*)(ws + 54525952);     // 50.3 MB
    float*  Zc    = (float*) (ws + 104857600);    // 16.8 MB
    bf16_t* Zp    = (bf16_t*)(ws + 121634816);    // 33.5 MB
    bf16_t* vT_g  = (bf16_t*)(ws + 0);            // 8.4 MB, overlays dead xb
    bf16_t* Ob    = (bf16_t*)(ws + 8388608);      // 33.5 MB, overlays dead xb/WinT

    float* outMain  = (float*)d_out;
    float* outState = (float*)d_out + (size_t)S_TOT * OUT_D;

    prep<<<16384 + 1536 + 1024, 256, 0, stream>>>(x, xb, W_in, WinT, W_out, WoutT);
    gemm_p2<1><<<1536, 256, 0, stream>>>(xb, WinT, proj, S_TOT, QKV, D_IN, 24);
    kv_fused<<<1024, 64, 0, stream>>>(proj, vT_g, Zc);
    prefix_state<<<1024, 256, 0, stream>>>(Zc, S0, Zp, outState);
    attn_chunk<<<1024, 256, 0, stream>>>(proj, vT_g, Zp, Ob);
    gemm_p2<0><<<1024, 256, 0, stream>>>(Ob, WoutT, outMain, S_TOT, OUT_D, OUT_D, 16);
}